// Round 4
// baseline (506.823 us; speedup 1.0000x reference)
//
#include <hip/hip_runtime.h>
#include <math.h>

#define BATCH 32
#define CHAN  512
#define HW    4096   // 64*64

typedef float floatx4 __attribute__((ext_vector_type(4)));

// Kernel 1: per-(b,c) spatial mean. One WAVE (64 lanes) per plane:
// each lane reads 16 x float4 (256 B) -> shuffle reduce. No LDS/barriers.
// y stores are agent-scope RELEASE atomics so they are coherent across XCDs
// for the consumer kernel even under graph replay (no reliance on inter-node
// cache maintenance).
__global__ __launch_bounds__(256) void mean_kernel(const float* __restrict__ x,
                                                   float* __restrict__ y) {
    int plane = (blockIdx.x * 256 + threadIdx.x) >> 6;   // global wave id
    int lane  = threadIdx.x & 63;
    const floatx4* xp = (const floatx4*)(x + (size_t)plane * HW);
    floatx4 a = (floatx4)(0.f);
#pragma unroll
    for (int i = 0; i < 16; ++i) a += xp[lane + i * 64];
    float s = (a.x + a.y) + (a.z + a.w);
    for (int off = 32; off; off >>= 1) s += __shfl_down(s, off, 64);
    if (lane == 0)
        __hip_atomic_store(&y[plane], s * (1.0f / HW),
                           __ATOMIC_RELEASE, __HIP_MEMORY_SCOPE_AGENT);
}

// Kernel 2 (fused): each block = one (b,k) output plane. Block recomputes the
// batch's conv1d(k=3)+sigmoid+top-3 from y (identical arithmetic in all 3
// blocks of a batch -> consistent indices), then copies plane x[b, idx_k].
// Tie rule matches lax.top_k: value desc, smaller index wins on exact tie.
__global__ __launch_bounds__(256) void topk_gather_kernel(const float* __restrict__ x,
                                                          const float* __restrict__ y,
                                                          const float* __restrict__ w,
                                                          float* __restrict__ out) {
    int blk = blockIdx.x;        // b*3 + k
    int b   = blk / 3;
    int kth = blk % 3;
    int t   = threadIdx.x;       // 0..255

    __shared__ float ym[CHAN];
    __shared__ float sv[CHAN];
    __shared__ float rv[256];
    __shared__ int   ri[256];

    // Agent-scope ACQUIRE loads: coherent view of y regardless of which XCD
    // wrote it.
    ym[t]       = __hip_atomic_load(&y[b * CHAN + t],
                                    __ATOMIC_ACQUIRE, __HIP_MEMORY_SCOPE_AGENT);
    ym[t + 256] = __hip_atomic_load(&y[b * CHAN + t + 256],
                                    __ATOMIC_ACQUIRE, __HIP_MEMORY_SCOPE_AGENT);
    __syncthreads();

    float w0 = w[0], w1 = w[1], w2 = w[2];
#pragma unroll
    for (int h = 0; h < 2; ++h) {
        int c = t + h * 256;
        float left  = (c > 0)        ? ym[c - 1] : 0.f;   // zero padding
        float right = (c < CHAN - 1) ? ym[c + 1] : 0.f;
        float s = w0 * left + w1 * ym[c] + w2 * right;    // lax conv = correlation
        sv[c] = 1.f / (1.f + expf(-s));                   // sigmoid
    }
    __syncthreads();

    int my_ch = 0;
    for (int pass = 0; pass < 3; ++pass) {
        // per-thread best of its 2 channels (tie -> smaller index = t)
        float v0 = sv[t], v1 = sv[t + 256];
        float bv; int bi;
        if (v1 > v0) { bv = v1; bi = t + 256; } else { bv = v0; bi = t; }
        rv[t] = bv; ri[t] = bi;
        __syncthreads();
        for (int stride = 128; stride > 0; stride >>= 1) {
            if (t < stride) {
                float v2 = rv[t + stride];
                int   i2 = ri[t + stride];
                if (v2 > rv[t] || (v2 == rv[t] && i2 < ri[t])) {
                    rv[t] = v2; ri[t] = i2;
                }
            }
            __syncthreads();
        }
        int winner = ri[0];
        if (pass == kth) my_ch = winner;
        __syncthreads();                 // everyone has read ri[0] / sv
        if (t == 0) sv[winner] = -1.0f;  // sigmoid >= 0, removes from later passes
        __syncthreads();                 // update visible before next pass
    }

    // copy plane x[b, my_ch] -> out[blk]
    const floatx4* src = (const floatx4*)(x + ((size_t)b * CHAN + my_ch) * HW);
    floatx4*       dst = (floatx4*)(out + (size_t)blk * HW);
#pragma unroll
    for (int i = 0; i < 4; ++i) dst[t + i * 256] = src[t + i * 256];
}

extern "C" void kernel_launch(void* const* d_in, const int* in_sizes, int n_in,
                              void* d_out, int out_size, void* d_ws, size_t ws_size,
                              hipStream_t stream) {
    const float* x  = (const float*)d_in[0];   // (32,512,64,64)
    const float* cw = (const float*)d_in[1];   // (1,1,3)
    float* out = (float*)d_out;                // (32,3,64,64)

    float* y = (float*)d_ws;                   // 32*512 floats = 64 KB

    mean_kernel<<<(BATCH * CHAN) / 4, 256, 0, stream>>>(x, y);
    topk_gather_kernel<<<BATCH * 3, 256, 0, stream>>>(x, y, cw, out);
}

// Round 5
// 48.929 us; speedup vs baseline: 10.3583x; 10.3583x over previous
//
#include <hip/hip_runtime.h>
#include <math.h>

#define BATCH 32
#define CHAN  512
#define HW    4096   // 64*64

typedef float floatx4 __attribute__((ext_vector_type(4)));

// Kernel 1: per-(b,c) spatial mean. One WAVE (64 lanes) per plane:
// each lane reads 16 x float4 (256 B) -> shuffle reduce. No LDS/barriers.
// y is written with RELAXED agent-scope atomic stores: these compile to a
// plain global_store with sc0/sc1 cache-bypass flags (write-through to the
// coherent point) and NO fence/cache-maintenance instructions — unlike
// RELEASE, which emitted per-wave L2 writebacks and cost 40x (R4: 180 GB/s).
__global__ __launch_bounds__(256) void mean_kernel(const float* __restrict__ x,
                                                   float* __restrict__ y) {
    int plane = (blockIdx.x * 256 + threadIdx.x) >> 6;   // global wave id
    int lane  = threadIdx.x & 63;
    const floatx4* xp = (const floatx4*)(x + (size_t)plane * HW);
    floatx4 a = (floatx4)(0.f);
#pragma unroll
    for (int i = 0; i < 16; ++i) a += xp[lane + i * 64];   // plain cached loads
    float s = (a.x + a.y) + (a.z + a.w);
    for (int off = 32; off; off >>= 1) s += __shfl_down(s, off, 64);
    if (lane == 0)
        __hip_atomic_store(&y[plane], s * (1.0f / HW),
                           __ATOMIC_RELAXED, __HIP_MEMORY_SCOPE_AGENT);
}

// Kernel 2 (fused): each block = one (b,k) output plane. Block recomputes the
// batch's conv1d(k=3)+sigmoid+top-3 from y (identical arithmetic in all 3
// blocks of a batch -> consistent indices), then copies plane x[b, idx_k].
// y reads are RELAXED agent-scope (sc0/sc1 load from the coherent point,
// no buffer_inv) — immune to stale per-XCD L2 lines under graph replay.
// Tie rule matches lax.top_k: value desc, smaller index wins on exact tie.
__global__ __launch_bounds__(256) void topk_gather_kernel(const float* __restrict__ x,
                                                          const float* __restrict__ y,
                                                          const float* __restrict__ w,
                                                          float* __restrict__ out) {
    int blk = blockIdx.x;        // b*3 + k
    int b   = blk / 3;
    int kth = blk % 3;
    int t   = threadIdx.x;       // 0..255

    __shared__ float ym[CHAN];
    __shared__ float sv[CHAN];
    __shared__ float rv[256];
    __shared__ int   ri[256];

    ym[t]       = __hip_atomic_load(&y[b * CHAN + t],
                                    __ATOMIC_RELAXED, __HIP_MEMORY_SCOPE_AGENT);
    ym[t + 256] = __hip_atomic_load(&y[b * CHAN + t + 256],
                                    __ATOMIC_RELAXED, __HIP_MEMORY_SCOPE_AGENT);
    __syncthreads();

    float w0 = w[0], w1 = w[1], w2 = w[2];
#pragma unroll
    for (int h = 0; h < 2; ++h) {
        int c = t + h * 256;
        float left  = (c > 0)        ? ym[c - 1] : 0.f;   // zero padding
        float right = (c < CHAN - 1) ? ym[c + 1] : 0.f;
        float s = w0 * left + w1 * ym[c] + w2 * right;    // lax conv = correlation
        sv[c] = 1.f / (1.f + expf(-s));                   // sigmoid
    }
    __syncthreads();

    int my_ch = 0;
    for (int pass = 0; pass < 3; ++pass) {
        // per-thread best of its 2 channels (tie -> smaller index = t)
        float v0 = sv[t], v1 = sv[t + 256];
        float bv; int bi;
        if (v1 > v0) { bv = v1; bi = t + 256; } else { bv = v0; bi = t; }
        rv[t] = bv; ri[t] = bi;
        __syncthreads();
        for (int stride = 128; stride > 0; stride >>= 1) {
            if (t < stride) {
                float v2 = rv[t + stride];
                int   i2 = ri[t + stride];
                if (v2 > rv[t] || (v2 == rv[t] && i2 < ri[t])) {
                    rv[t] = v2; ri[t] = i2;
                }
            }
            __syncthreads();
        }
        int winner = ri[0];
        if (pass == kth) my_ch = winner;
        __syncthreads();                 // everyone has read ri[0] / sv
        if (t == 0) sv[winner] = -1.0f;  // sigmoid >= 0, removes from later passes
        __syncthreads();                 // update visible before next pass
    }

    // copy plane x[b, my_ch] -> out[blk]
    const floatx4* src = (const floatx4*)(x + ((size_t)b * CHAN + my_ch) * HW);
    floatx4*       dst = (floatx4*)(out + (size_t)blk * HW);
#pragma unroll
    for (int i = 0; i < 4; ++i) dst[t + i * 256] = src[t + i * 256];
}

extern "C" void kernel_launch(void* const* d_in, const int* in_sizes, int n_in,
                              void* d_out, int out_size, void* d_ws, size_t ws_size,
                              hipStream_t stream) {
    const float* x  = (const float*)d_in[0];   // (32,512,64,64)
    const float* cw = (const float*)d_in[1];   // (1,1,3)
    float* out = (float*)d_out;                // (32,3,64,64)

    float* y = (float*)d_ws;                   // 32*512 floats = 64 KB

    mean_kernel<<<(BATCH * CHAN) / 4, 256, 0, stream>>>(x, y);
    topk_gather_kernel<<<BATCH * 3, 256, 0, stream>>>(x, y, cw, out);
}

// Round 6
// 48.474 us; speedup vs baseline: 10.4556x; 1.0094x over previous
//
#include <hip/hip_runtime.h>
#include <math.h>

#define BATCH 32
#define CHAN  512
#define HW    4096   // 64*64

typedef float floatx4 __attribute__((ext_vector_type(4)));

// Kernel 1: per-(b,c) spatial mean. One WAVE (64 lanes) per plane:
// each lane reads 16 x float4 (256 B) -> shuffle reduce. No LDS/barriers.
// y is written with RELAXED agent-scope atomic stores: plain global_store
// with cache-bypass to the coherent point, NO fences (RELEASE cost 40x, R4).
__global__ __launch_bounds__(256) void mean_kernel(const float* __restrict__ x,
                                                   float* __restrict__ y) {
    int plane = (blockIdx.x * 256 + threadIdx.x) >> 6;   // global wave id
    int lane  = threadIdx.x & 63;
    const floatx4* xp = (const floatx4*)(x + (size_t)plane * HW);
    floatx4 a = (floatx4)(0.f);
#pragma unroll
    for (int i = 0; i < 16; ++i) a += xp[lane + i * 64];   // plain cached loads
    float s = (a.x + a.y) + (a.z + a.w);
    for (int off = 32; off; off >>= 1) s += __shfl_down(s, off, 64);
    if (lane == 0)
        __hip_atomic_store(&y[plane], s * (1.0f / HW),
                           __ATOMIC_RELAXED, __HIP_MEMORY_SCOPE_AGENT);
}

// Kernel 2 (fused): each block = one (b,k) output plane. Block recomputes the
// batch's conv1d(k=3)+sigmoid+top-3 from y, then copies plane x[b, idx_k].
// Top-3 is register-resident + wave-parallel: each lane holds 8 sigmoid
// values (channel = j*64+lane); per pass a lane-local argmax (strict >, j
// ascending => min-index tie rule) then a 6-level shfl_xor butterfly with
// the lax.top_k combine (value desc, index asc). Only 2 barriers total
// (vs ~27 for the LDS tree version). All 4 waves compute identical results.
__global__ __launch_bounds__(256) void topk_gather_kernel(const float* __restrict__ x,
                                                          const float* __restrict__ y,
                                                          const float* __restrict__ w,
                                                          float* __restrict__ out) {
    int blk  = blockIdx.x;        // b*3 + k
    int b    = blk / 3;
    int kth  = blk % 3;
    int t    = threadIdx.x;       // 0..255
    int lane = t & 63;

    __shared__ float ym[CHAN];
    __shared__ float sv[CHAN];

    // Relaxed agent-scope loads: coherent view of y across XCDs, no fences.
    ym[t]       = __hip_atomic_load(&y[b * CHAN + t],
                                    __ATOMIC_RELAXED, __HIP_MEMORY_SCOPE_AGENT);
    ym[t + 256] = __hip_atomic_load(&y[b * CHAN + t + 256],
                                    __ATOMIC_RELAXED, __HIP_MEMORY_SCOPE_AGENT);
    __syncthreads();

    float w0 = w[0], w1 = w[1], w2 = w[2];
#pragma unroll
    for (int h = 0; h < 2; ++h) {
        int c = t + h * 256;
        float left  = (c > 0)        ? ym[c - 1] : 0.f;   // zero padding
        float right = (c < CHAN - 1) ? ym[c + 1] : 0.f;
        float s = w0 * left + w1 * ym[c] + w2 * right;    // lax conv = correlation
        sv[c] = 1.f / (1.f + expf(-s));                   // sigmoid in (0,1)
    }
    __syncthreads();

    // lane-resident copy: v[j] = sv[j*64 + lane] (stride-1 across lanes, no conflicts)
    float v[8];
#pragma unroll
    for (int j = 0; j < 8; ++j) v[j] = sv[j * 64 + lane];

    int my_ch = 0;
    for (int pass = 0; pass < 3; ++pass) {
        // lane-local argmax over 8 (ascending channel index, strict > keeps min index)
        float bv = v[0]; int bi = lane;
#pragma unroll
        for (int j = 1; j < 8; ++j) {
            if (v[j] > bv) { bv = v[j]; bi = j * 64 + lane; }
        }
        // 64-lane butterfly argmax: value desc, smaller index on exact tie
#pragma unroll
        for (int m = 1; m < 64; m <<= 1) {
            float ov = __shfl_xor(bv, m, 64);
            int   oi = __shfl_xor(bi, m, 64);
            if (ov > bv || (ov == bv && oi < bi)) { bv = ov; bi = oi; }
        }
        if (pass == kth) my_ch = bi;
        // mask the winner in-register (sigmoid > 0 > -1)
        int wj = bi >> 6, wl = bi & 63;
        if (lane == wl) v[wj] = -1.0f;
    }

    // copy plane x[b, my_ch] -> out[blk]
    const floatx4* src = (const floatx4*)(x + ((size_t)b * CHAN + my_ch) * HW);
    floatx4*       dst = (floatx4*)(out + (size_t)blk * HW);
#pragma unroll
    for (int i = 0; i < 4; ++i) dst[t + i * 256] = src[t + i * 256];
}

extern "C" void kernel_launch(void* const* d_in, const int* in_sizes, int n_in,
                              void* d_out, int out_size, void* d_ws, size_t ws_size,
                              hipStream_t stream) {
    const float* x  = (const float*)d_in[0];   // (32,512,64,64)
    const float* cw = (const float*)d_in[1];   // (1,1,3)
    float* out = (float*)d_out;                // (32,3,64,64)

    float* y = (float*)d_ws;                   // 32*512 floats = 64 KB

    mean_kernel<<<(BATCH * CHAN) / 4, 256, 0, stream>>>(x, y);
    topk_gather_kernel<<<BATCH * 3, 256, 0, stream>>>(x, y, cw, out);
}